// Round 4
// baseline (335.299 us; speedup 1.0000x reference)
//
#include <hip/hip_runtime.h>
#include <stdint.h>

// out[b,s,u] = (LN(x) @ ternary(W)) * mean|W|   (reference's gamma absmax cancels)
// Fused: absum -> ternarize into MFMA-frag-packed wqP -> [LN + i8 quant + barrier-free GEMM].
// Round 4: 8 waves/block (512 thr), acc 32 regs/wave, depth-4 B prefetch ->
// 4 waves/SIMD so L2 latency is covered. Same validated wqP packing + sA swizzle.
// x: (4,8192,1024) fp32. M=32768, K=1024, N=1024, out fp32.

#define M_ROWS 32768
#define KDIM 1024
#define NDIM 1024

typedef int v4i  __attribute__((ext_vector_type(4)));
typedef int v16i __attribute__((ext_vector_type(16)));

// ---------------- kernel 1: |w| partial sums (no atomics, no memset) ------------
__global__ __launch_bounds__(256) void absum_k(const float* __restrict__ w,
                                               float* __restrict__ partials) {
    int idx = blockIdx.x * 256 + threadIdx.x;
    float4 v = ((const float4*)w)[idx];
    float s = fabsf(v.x) + fabsf(v.y) + fabsf(v.z) + fabsf(v.w);
    #pragma unroll
    for (int o = 32; o; o >>= 1) s += __shfl_xor(s, o);
    __shared__ float p[4];
    if ((threadIdx.x & 63) == 0) p[threadIdx.x >> 6] = s;
    __syncthreads();
    if (threadIdx.x == 0) partials[blockIdx.x] = p[0] + p[1] + p[2] + p[3];
}

// ------- kernel 2: ternarize -> wqP packed MFMA-frag-major ----------------------
// Frag (nb, s): lane l holds B[n=nb*32+(l&31)][k=s*32+(l>>5)*16 .. +16], stored as
// 64 contiguous 16B units at wqP[((nb*32+s)*64 + l)*16]. One wave-load = 1KB linear.
__global__ __launch_bounds__(256) void quant_k(const float* __restrict__ w,
                                               const float* __restrict__ partials,
                                               char* __restrict__ wqP,
                                               float* __restrict__ wsum) {
    int t = threadIdx.x;
    float s = partials[t] + partials[t + 256] + partials[t + 512] + partials[t + 768];
    #pragma unroll
    for (int o = 32; o; o >>= 1) s += __shfl_xor(s, o);
    __shared__ float ps[4];
    if ((t & 63) == 0) ps[t >> 6] = s;
    __syncthreads();
    float total = ps[0] + ps[1] + ps[2] + ps[3];
    if (blockIdx.x == 0 && t == 0) wsum[0] = total;
    float beta = total * (1.0f / 1048576.0f);
    float inv  = 1.0f / (beta + 1e-5f);

    __shared__ char sT[64 * 80];           // [n][k], stride 80 (16B-aligned rows)
    int k0 = (blockIdx.x >> 4) * 64, n0 = (blockIdx.x & 15) * 64;
    int n_l = t & 63;
    #pragma unroll
    for (int r = 0; r < 16; ++r) {
        int k_l = (t >> 6) * 16 + r;
        float q = rintf(w[(size_t)(k0 + k_l) * NDIM + n0 + n_l] * inv);
        q = fminf(1.0f, fmaxf(-1.0f, q));
        sT[n_l * 80 + k_l] = (char)(int)q;
    }
    __syncthreads();
    int nn = t >> 2, c = t & 3;
    v4i val = *(const v4i*)&sT[nn * 80 + c * 16];
    int n = n0 + nn, k = k0 + c * 16;
    int idx = ((n >> 5) * 32 + (k >> 5)) * 64 + (n & 31) + ((k >> 4) & 1) * 32;
    *(v4i*)&wqP[(size_t)idx * 16] = val;
}

// ---------------- kernel 3: fused LN + i8 quant + barrier-free i8 GEMM ----------
// 512 thr (8 waves), BM=64 rows, full N=1024. LDS = sA 64KB frag-major + scales
// -> 2 blocks/CU = 16 waves/CU = 4 waves/SIMD (regs capped at 128 by launch_bounds).
// sA: per mf-block (32 rows), unit u = k/16 (0..63), 32 slots x 16B,
// slot = (row&31) ^ (u&7): char4 writes 2-way-bank (free), ds_read_b128 min-cycle.
// Phase 2: ONE barrier. 4 passes; wave owns 64m x 32n/pass; acc = 2x16 regs;
// B depth-4 + A depth-4 register pipeline, 2 MFMA per frag; per-pass epilogue.
__global__ __launch_bounds__(512, 4) void ln_gemm_k(const float* __restrict__ x,
                                                    const float* __restrict__ g,
                                                    const float* __restrict__ bln,
                                                    const char* __restrict__ wqP,
                                                    const float* __restrict__ wsum,
                                                    float* __restrict__ out) {
    __shared__ char  sA[64 * 1024];
    __shared__ float sScl[64];

    int t = threadIdx.x;
    int w = t >> 6, lane = t & 63;
    int half = lane >> 5, l31 = lane & 31;
    int bm0 = blockIdx.x * 64;

    // ---- phase 1: LN + per-row quant into frag-major sA (wave: 8 rows) ----
    float4 g4[4], b4[4];
    #pragma unroll
    for (int j = 0; j < 4; ++j) {
        g4[j] = ((const float4*)g)[lane + 64 * j];
        b4[j] = ((const float4*)bln)[lane + 64 * j];
    }
    #pragma unroll 2
    for (int rr = 0; rr < 8; ++rr) {
        int row = w * 8 + rr;
        const float4* xr = (const float4*)(x + ((size_t)(bm0 + row) << 10));
        float4 v0 = xr[lane], v1 = xr[lane + 64], v2 = xr[lane + 128], v3 = xr[lane + 192];
        float s  = v0.x + v0.y + v0.z + v0.w + v1.x + v1.y + v1.z + v1.w
                 + v2.x + v2.y + v2.z + v2.w + v3.x + v3.y + v3.z + v3.w;
        float ss = v0.x*v0.x + v0.y*v0.y + v0.z*v0.z + v0.w*v0.w
                 + v1.x*v1.x + v1.y*v1.y + v1.z*v1.z + v1.w*v1.w
                 + v2.x*v2.x + v2.y*v2.y + v2.z*v2.z + v2.w*v2.w
                 + v3.x*v3.x + v3.y*v3.y + v3.z*v3.z + v3.w*v3.w;
        #pragma unroll
        for (int o = 32; o; o >>= 1) { s += __shfl_xor(s, o); ss += __shfl_xor(ss, o); }
        float mu  = s * (1.0f / 1024.0f);
        float var = ss * (1.0f / 1024.0f) - mu * mu;
        float rs  = rsqrtf(var + 1e-3f);        // keras LN eps
        float xn[16];
        float mx = 0.f;
        #define LNQ(j, vv) do { \
            xn[4*(j)+0] = (vv.x - mu) * rs * g4[j].x + b4[j].x; \
            xn[4*(j)+1] = (vv.y - mu) * rs * g4[j].y + b4[j].y; \
            xn[4*(j)+2] = (vv.z - mu) * rs * g4[j].z + b4[j].z; \
            xn[4*(j)+3] = (vv.w - mu) * rs * g4[j].w + b4[j].w; \
            mx = fmaxf(mx, fmaxf(fmaxf(fabsf(xn[4*(j)+0]), fabsf(xn[4*(j)+1])), \
                                 fmaxf(fabsf(xn[4*(j)+2]), fabsf(xn[4*(j)+3])))); \
        } while (0)
        LNQ(0, v0); LNQ(1, v1); LNQ(2, v2); LNQ(3, v3);
        #undef LNQ
        #pragma unroll
        for (int o = 32; o; o >>= 1) mx = fmaxf(mx, __shfl_xor(mx, o));
        mx = fmaxf(mx, 1e-20f);
        float inv = 127.0f / mx;
        if (lane == 0) sScl[row] = mx * (1.0f / 127.0f);
        int mf = row >> 5, r31 = row & 31;
        #pragma unroll
        for (int j = 0; j < 4; ++j) {
            // lane's float4 j covers k = 4*(lane + 64j) .. +3 -> one char4
            char4 c4;
            c4.x = (char)(int)rintf(xn[4*j+0] * inv);
            c4.y = (char)(int)rintf(xn[4*j+1] * inv);
            c4.z = (char)(int)rintf(xn[4*j+2] * inv);
            c4.w = (char)(int)rintf(xn[4*j+3] * inv);
            int u    = (lane >> 2) + 16 * j;          // 16B unit = k>>4
            int slot = r31 ^ (u & 7);
            *(char4*)&sA[mf * 32768 + (u * 32 + slot) * 16 + (lane & 3) * 4] = c4;
        }
    }
    __syncthreads();                              // the ONLY barrier

    // ---- phase 2: barrier-free GEMM. 4 passes; wave w owns nb = p*8+w. ----
    float beta = wsum[0] * (1.0f / 1048576.0f);
    const v4i* wp = (const v4i*)wqP;

    // A frag (mf, S): unit u = 2S+half, slot = l31 ^ (u&7)
    #define LA(dst, S) do { \
        int u_ = 2 * (S) + half; \
        int o_ = ((u_ * 32) + (l31 ^ (u_ & 7))) * 16; \
        dst[0] = *(const v4i*)&sA[o_]; \
        dst[1] = *(const v4i*)&sA[o_ + 32768]; \
    } while (0)

    #pragma unroll 1
    for (int p = 0; p < 4; ++p) {
        int nb = p * 8 + w;
        size_t fb = (size_t)nb * 32 * 64;        // frag base (v4i units)
        v16i acc0 = {}, acc1 = {};
        v4i a0[2], a1[2], a2[2], a3[2], b0, b1, b2, b3;

        b0 = wp[fb + 0 * 64 + lane];
        b1 = wp[fb + 1 * 64 + lane];
        b2 = wp[fb + 2 * 64 + lane];
        b3 = wp[fb + 3 * 64 + lane];
        LA(a0, 0); LA(a1, 1); LA(a2, 2); LA(a3, 3);

        #pragma unroll 1
        for (int s = 0; s < 32; s += 4) {
            acc0 = __builtin_amdgcn_mfma_i32_32x32x32_i8(a0[0], b0, acc0, 0, 0, 0);
            acc1 = __builtin_amdgcn_mfma_i32_32x32x32_i8(a0[1], b0, acc1, 0, 0, 0);
            if (s + 4 < 32) { b0 = wp[fb + (size_t)(s + 4) * 64 + lane]; LA(a0, s + 4); }
            acc0 = __builtin_amdgcn_mfma_i32_32x32x32_i8(a1[0], b1, acc0, 0, 0, 0);
            acc1 = __builtin_amdgcn_mfma_i32_32x32x32_i8(a1[1], b1, acc1, 0, 0, 0);
            if (s + 5 < 32) { b1 = wp[fb + (size_t)(s + 5) * 64 + lane]; LA(a1, s + 5); }
            acc0 = __builtin_amdgcn_mfma_i32_32x32x32_i8(a2[0], b2, acc0, 0, 0, 0);
            acc1 = __builtin_amdgcn_mfma_i32_32x32x32_i8(a2[1], b2, acc1, 0, 0, 0);
            if (s + 6 < 32) { b2 = wp[fb + (size_t)(s + 6) * 64 + lane]; LA(a2, s + 6); }
            acc0 = __builtin_amdgcn_mfma_i32_32x32x32_i8(a3[0], b3, acc0, 0, 0, 0);
            acc1 = __builtin_amdgcn_mfma_i32_32x32x32_i8(a3[1], b3, acc1, 0, 0, 0);
            if (s + 7 < 32) { b3 = wp[fb + (size_t)(s + 7) * 64 + lane]; LA(a3, s + 7); }
        }

        // per-pass epilogue: out-writes overlap next pass's compute
        #pragma unroll
        for (int r = 0; r < 16; ++r) {
            // C/D 32x32: col = lane&31, row = (r&3) + 8*(r>>2) + 4*(lane>>5)
            int rl = (r & 3) + 8 * (r >> 2) + 4 * half;
            float sc0 = sScl[rl] * beta;
            float sc1 = sScl[32 + rl] * beta;
            size_t o = (size_t)(bm0 + rl) * NDIM + nb * 32 + l31;
            out[o]                      = (float)acc0[r] * sc0;
            out[o + (size_t)32 * NDIM]  = (float)acc1[r] * sc1;
        }
    }
    #undef LA
}

extern "C" void kernel_launch(void* const* d_in, const int* in_sizes, int n_in,
                              void* d_out, int out_size, void* d_ws, size_t ws_size,
                              hipStream_t stream) {
    const float* x        = (const float*)d_in[0];   // 4*8192*1024
    const float* weight   = (const float*)d_in[1];   // 1024*1024
    const float* ln_gamma = (const float*)d_in[2];   // 1024
    const float* ln_beta  = (const float*)d_in[3];   // 1024
    float* out = (float*)d_out;

    // ws layout: [0,4) wsum | [4K, 8K) partials(1024 f32) | [256K, 256K+1M) wqP i8
    float* wsum     = (float*)d_ws;
    float* partials = (float*)((char*)d_ws + 4096);
    char*  wqP      = (char*)d_ws + (1u << 18);

    absum_k<<<1024, 256, 0, stream>>>(weight, partials);
    quant_k<<<256, 256, 0, stream>>>(weight, partials, wqP, wsum);
    ln_gemm_k<<<M_ROWS / 64, 512, 0, stream>>>(x, ln_gamma, ln_beta, wqP, wsum, out);
}

// Round 5
// 283.051 us; speedup vs baseline: 1.1846x; 1.1846x over previous
//
#include <hip/hip_runtime.h>
#include <stdint.h>

// out[b,s,u] = (LN(x) @ ternary(W)) * mean|W|   (reference's gamma absmax cancels)
// Fused: absum -> ternarize into MFMA-frag-packed wqP -> [LN + i8 quant + barrier-free GEMM].
// Round 5: fit the 64-arch-VGPR quantum that __launch_bounds__(512,4) imposes
// (R4 spilled: FETCH +94MB scratch). B depth-4 rolling + A depth-2 dbuf + acc 32.
// x: (4,8192,1024) fp32. M=32768, K=1024, N=1024, out fp32.

#define M_ROWS 32768
#define KDIM 1024
#define NDIM 1024

typedef int v4i  __attribute__((ext_vector_type(4)));
typedef int v16i __attribute__((ext_vector_type(16)));

// ---------------- kernel 1: |w| partial sums (no atomics, no memset) ------------
__global__ __launch_bounds__(256) void absum_k(const float* __restrict__ w,
                                               float* __restrict__ partials) {
    int idx = blockIdx.x * 256 + threadIdx.x;
    float4 v = ((const float4*)w)[idx];
    float s = fabsf(v.x) + fabsf(v.y) + fabsf(v.z) + fabsf(v.w);
    #pragma unroll
    for (int o = 32; o; o >>= 1) s += __shfl_xor(s, o);
    __shared__ float p[4];
    if ((threadIdx.x & 63) == 0) p[threadIdx.x >> 6] = s;
    __syncthreads();
    if (threadIdx.x == 0) partials[blockIdx.x] = p[0] + p[1] + p[2] + p[3];
}

// ------- kernel 2: ternarize -> wqP packed MFMA-frag-major ----------------------
// Frag (nb, s): lane l holds B[n=nb*32+(l&31)][k=s*32+(l>>5)*16 .. +16], stored as
// 64 contiguous 16B units at wqP[((nb*32+s)*64 + l)*16]. One wave-load = 1KB linear.
__global__ __launch_bounds__(256) void quant_k(const float* __restrict__ w,
                                               const float* __restrict__ partials,
                                               char* __restrict__ wqP,
                                               float* __restrict__ wsum) {
    int t = threadIdx.x;
    float s = partials[t] + partials[t + 256] + partials[t + 512] + partials[t + 768];
    #pragma unroll
    for (int o = 32; o; o >>= 1) s += __shfl_xor(s, o);
    __shared__ float ps[4];
    if ((t & 63) == 0) ps[t >> 6] = s;
    __syncthreads();
    float total = ps[0] + ps[1] + ps[2] + ps[3];
    if (blockIdx.x == 0 && t == 0) wsum[0] = total;
    float beta = total * (1.0f / 1048576.0f);
    float inv  = 1.0f / (beta + 1e-5f);

    __shared__ char sT[64 * 80];           // [n][k], stride 80 (16B-aligned rows)
    int k0 = (blockIdx.x >> 4) * 64, n0 = (blockIdx.x & 15) * 64;
    int n_l = t & 63;
    #pragma unroll
    for (int r = 0; r < 16; ++r) {
        int k_l = (t >> 6) * 16 + r;
        float q = rintf(w[(size_t)(k0 + k_l) * NDIM + n0 + n_l] * inv);
        q = fminf(1.0f, fmaxf(-1.0f, q));
        sT[n_l * 80 + k_l] = (char)(int)q;
    }
    __syncthreads();
    int nn = t >> 2, c = t & 3;
    v4i val = *(const v4i*)&sT[nn * 80 + c * 16];
    int n = n0 + nn, k = k0 + c * 16;
    int idx = ((n >> 5) * 32 + (k >> 5)) * 64 + (n & 31) + ((k >> 4) & 1) * 32;
    *(v4i*)&wqP[(size_t)idx * 16] = val;
}

// ---------------- kernel 3: fused LN + i8 quant + barrier-free i8 GEMM ----------
// 512 thr (8 waves), BM=64, full N=1024; LDS 64KB sA -> 2 blocks/CU = 4 waves/SIMD.
// (512,4) imposes 64 arch VGPRs/wave (HW 64-reg quantum); phase-2 live set kept
// under it: B depth-4 rolling (16) + A depth-2 dbuf (16) + acc in accum file (32).
// sA frag-major: unit u = k/16, 32 slots x 16B, slot = (row&31) ^ (u&7) -> both
// char4 writes (2-way, free) and ds_read_b128 frag reads are conflict-free.
// Phase 2: ONE barrier total; 4 passes; wave owns 64m x 32n/pass; B-slot wrap
// (+16384) and A-slot wrap (&31) prefetch the next pass during the current one.
__global__ __launch_bounds__(512, 4) void ln_gemm_k(const float* __restrict__ x,
                                                    const float* __restrict__ g,
                                                    const float* __restrict__ bln,
                                                    const char* __restrict__ wqP,
                                                    const float* __restrict__ wsum,
                                                    float* __restrict__ out) {
    __shared__ char  sA[64 * 1024];
    __shared__ float sScl[64];

    int t = threadIdx.x;
    int w = t >> 6, lane = t & 63;
    int half = lane >> 5, l31 = lane & 31;
    int bm0 = blockIdx.x * 64;

    const v4i* wp = (const v4i*)wqP;
    size_t fb = (size_t)w * 2048 + lane;     // pass-0 frag base for this wave
    // issue pass-0 B frags 0..3 before the barrier: overlap phase-1 tail
    v4i b0 = wp[fb], b1 = wp[fb + 64], b2 = wp[fb + 128], b3 = wp[fb + 192];

    // ---- phase 1: LN + per-row quant into frag-major sA (wave: 8 rows) ----
    #pragma unroll 1
    for (int rr = 0; rr < 8; ++rr) {
        int row = w * 8 + rr;
        const float4* xr = (const float4*)(x + ((size_t)(bm0 + row) << 10));
        float4 v0 = xr[lane], v1 = xr[lane + 64], v2 = xr[lane + 128], v3 = xr[lane + 192];
        float s  = v0.x + v0.y + v0.z + v0.w + v1.x + v1.y + v1.z + v1.w
                 + v2.x + v2.y + v2.z + v2.w + v3.x + v3.y + v3.z + v3.w;
        float ss = v0.x*v0.x + v0.y*v0.y + v0.z*v0.z + v0.w*v0.w
                 + v1.x*v1.x + v1.y*v1.y + v1.z*v1.z + v1.w*v1.w
                 + v2.x*v2.x + v2.y*v2.y + v2.z*v2.z + v2.w*v2.w
                 + v3.x*v3.x + v3.y*v3.y + v3.z*v3.z + v3.w*v3.w;
        #pragma unroll
        for (int o = 32; o; o >>= 1) { s += __shfl_xor(s, o); ss += __shfl_xor(ss, o); }
        float mu  = s * (1.0f / 1024.0f);
        float var = ss * (1.0f / 1024.0f) - mu * mu;
        float rs  = rsqrtf(var + 1e-3f);        // keras LN eps
        float xn[16];
        float4 vv[4] = {v0, v1, v2, v3};
        float mx = 0.f;
        #pragma unroll
        for (int j = 0; j < 4; ++j) {           // gamma/beta loaded per-j: L1-hot,
            float4 gg = ((const float4*)g)[lane + 64 * j];   // keeps peak regs < 64
            float4 bb = ((const float4*)bln)[lane + 64 * j];
            xn[4*j+0] = (vv[j].x - mu) * rs * gg.x + bb.x;
            xn[4*j+1] = (vv[j].y - mu) * rs * gg.y + bb.y;
            xn[4*j+2] = (vv[j].z - mu) * rs * gg.z + bb.z;
            xn[4*j+3] = (vv[j].w - mu) * rs * gg.w + bb.w;
            #pragma unroll
            for (int e = 0; e < 4; ++e) mx = fmaxf(mx, fabsf(xn[4*j+e]));
        }
        #pragma unroll
        for (int o = 32; o; o >>= 1) mx = fmaxf(mx, __shfl_xor(mx, o));
        mx = fmaxf(mx, 1e-20f);
        float inv = 127.0f / mx;
        if (lane == 0) sScl[row] = mx * (1.0f / 127.0f);
        int mf = row >> 5, r31 = row & 31;
        #pragma unroll
        for (int j = 0; j < 4; ++j) {
            // lane's float4 j covers k = 4*(lane + 64j) .. +3 -> one char4
            char4 c4;
            c4.x = (char)(int)rintf(xn[4*j+0] * inv);
            c4.y = (char)(int)rintf(xn[4*j+1] * inv);
            c4.z = (char)(int)rintf(xn[4*j+2] * inv);
            c4.w = (char)(int)rintf(xn[4*j+3] * inv);
            int u    = (lane >> 2) + 16 * j;          // 16B unit = k>>4
            int slot = r31 ^ (u & 7);
            *(char4*)&sA[mf * 32768 + (u * 32 + slot) * 16 + (lane & 3) * 4] = c4;
        }
    }
    __syncthreads();                              // the ONLY barrier

    // ---- phase 2: barrier-free GEMM. 4 passes; wave w owns nb = p*8+w. ----
    float beta = wsum[0] * (1.0f / 1048576.0f);

    // A frag (both mf blocks) for step S: unit u = 2S+half, slot = l31 ^ (u&7)
    #define LA(dst, S) do { \
        int u_ = 2 * (S) + half; \
        int o_ = ((u_ * 32) + (l31 ^ (u_ & 7))) * 16; \
        dst[0] = *(const v4i*)&sA[o_]; \
        dst[1] = *(const v4i*)&sA[o_ + 32768]; \
    } while (0)
    // rolling B prefetch; q>=32 wraps into next pass's frags (fb advances +16384)
    #define BSEL(q_) wp[fb + (size_t)((q_) & 31) * 64 + ((((q_) >= 32) && (p < 3)) ? 16384u : 0u)]

    v4i aA[2], aB[2];
    LA(aA, 0); LA(aB, 1);

    #pragma unroll 1
    for (int p = 0; p < 4; ++p) {
        v16i acc0 = {}, acc1 = {};
        #pragma unroll 1
        for (int s = 0; s < 32; s += 4) {
            acc0 = __builtin_amdgcn_mfma_i32_32x32x32_i8(aA[0], b0, acc0, 0, 0, 0);
            acc1 = __builtin_amdgcn_mfma_i32_32x32x32_i8(aA[1], b0, acc1, 0, 0, 0);
            b0 = BSEL(s + 4);
            LA(aA, s + 2);
            acc0 = __builtin_amdgcn_mfma_i32_32x32x32_i8(aB[0], b1, acc0, 0, 0, 0);
            acc1 = __builtin_amdgcn_mfma_i32_32x32x32_i8(aB[1], b1, acc1, 0, 0, 0);
            b1 = BSEL(s + 5);
            LA(aB, s + 3);
            acc0 = __builtin_amdgcn_mfma_i32_32x32x32_i8(aA[0], b2, acc0, 0, 0, 0);
            acc1 = __builtin_amdgcn_mfma_i32_32x32x32_i8(aA[1], b2, acc1, 0, 0, 0);
            b2 = BSEL(s + 6);
            LA(aA, (s + 4) & 31);                 // s=28 -> frag 0 (next pass, same LDS)
            acc0 = __builtin_amdgcn_mfma_i32_32x32x32_i8(aB[0], b3, acc0, 0, 0, 0);
            acc1 = __builtin_amdgcn_mfma_i32_32x32x32_i8(aB[1], b3, acc1, 0, 0, 0);
            b3 = BSEL(s + 7);
            LA(aB, (s + 5) & 31);                 // s=28 -> frag 1
        }

        // per-pass epilogue: out-writes overlap next pass's compute (other waves)
        int nb = p * 8 + w;
        #pragma unroll
        for (int r = 0; r < 16; ++r) {
            // C/D 32x32: col = lane&31, row = (r&3) + 8*(r>>2) + 4*(lane>>5)
            int rl = (r & 3) + 8 * (r >> 2) + 4 * half;
            float sc0 = sScl[rl] * beta;
            float sc1 = sScl[32 + rl] * beta;
            size_t o = (size_t)(bm0 + rl) * NDIM + nb * 32 + l31;
            out[o]                     = (float)acc0[r] * sc0;
            out[o + (size_t)32 * NDIM] = (float)acc1[r] * sc1;
        }
        fb += 16384;                              // advance to next pass's frag base
    }
    #undef LA
    #undef BSEL
}

extern "C" void kernel_launch(void* const* d_in, const int* in_sizes, int n_in,
                              void* d_out, int out_size, void* d_ws, size_t ws_size,
                              hipStream_t stream) {
    const float* x        = (const float*)d_in[0];   // 4*8192*1024
    const float* weight   = (const float*)d_in[1];   // 1024*1024
    const float* ln_gamma = (const float*)d_in[2];   // 1024
    const float* ln_beta  = (const float*)d_in[3];   // 1024
    float* out = (float*)d_out;

    // ws layout: [0,4) wsum | [4K, 8K) partials(1024 f32) | [256K, 256K+1M) wqP i8
    float* wsum     = (float*)d_ws;
    float* partials = (float*)((char*)d_ws + 4096);
    char*  wqP      = (char*)d_ws + (1u << 18);

    absum_k<<<1024, 256, 0, stream>>>(weight, partials);
    quant_k<<<256, 256, 0, stream>>>(weight, partials, wqP, wsum);
    ln_gemm_k<<<M_ROWS / 64, 512, 0, stream>>>(x, ln_gamma, ln_beta, wqP, wsum, out);
}